// Round 3
// baseline (335.891 us; speedup 1.0000x reference)
//
#include <hip/hip_runtime.h>
#include <math.h>

#define H 2048

__device__ __forceinline__ float sigmoidf_(float v) {
    return 1.0f / (1.0f + expf(-v));
}

__device__ __forceinline__ float wave_reduce_sum(float v) {
    v += __shfl_down(v, 32, 64);
    v += __shfl_down(v, 16, 64);
    v += __shfl_down(v, 8, 64);
    v += __shfl_down(v, 4, 64);
    v += __shfl_down(v, 2, 64);
    v += __shfl_down(v, 1, 64);
    return v;
}

// Async global->LDS, 16 B per lane. lds_dst is the WAVE-UNIFORM base; HW
// writes lane*16B. gsrc is per-lane. (m97 pattern: compiler never emits this
// on its own, and __syncthreads() drains it via s_waitcnt vmcnt(0).)
__device__ __forceinline__ void gl_lds16(const float* gsrc, float* lds_dst) {
    __builtin_amdgcn_global_load_lds(
        (const __attribute__((address_space(1))) void*)gsrc,
        (__attribute__((address_space(3))) void*)lds_dst,
        16, 0, 0);
}

// Partial GEMV for layers 1,2: grid 4096 = {m=0: Wih, m=1: Whh} x 2048 t.
// Block: 256 thr = 4 waves = 4 gates. Wave w async-stages row (w*H + t) of
// its matrix into a private 8KB LDS buffer (whole block: 32KB in flight),
// one barrier, dot against the (L1-cached) input vector, reduce, write one
// partial gate value (+bias folded: bih into m=0, bhh into m=1).
__global__ __launch_bounds__(256)
void lstm_partial(const float* __restrict__ Wih, const float* __restrict__ Whh,
                  const float* __restrict__ bih, const float* __restrict__ bhh,
                  const float* __restrict__ xin,  // [H] input vector for Wih
                  const float* __restrict__ hin,  // [H] input vector for Whh
                  float* __restrict__ part)       // [2][4H] partial gates
{
    __shared__ float4 wbuf[4][512];  // 4 waves x 8KB = 32 KB
    const int bid = blockIdx.x;
    const int m = bid >> 11;         // 0..1
    const int t = bid & 2047;
    const int w = threadIdx.x >> 6;  // gate 0..3
    const int lane = threadIdx.x & 63;

    const float* W = m ? Whh : Wih;
    const float* v = m ? hin : xin;
    const float* barr = m ? bhh : bih;
    const float* row = W + (size_t)(w * H + t) * H;
    float* lbase = (float*)&wbuf[w][0];

    // fire all 8 async row-chunk loads (8 KB) — no VGPRs consumed
#pragma unroll
    for (int k = 0; k < 8; ++k)
        gl_lds16(row + k * 256 + lane * 4, lbase + k * 256);

    // input vector to registers (same 8KB for all blocks -> L1/L2 hits)
    float4 bv[8];
    const float4* v4 = (const float4*)v;
#pragma unroll
    for (int k = 0; k < 8; ++k) bv[k] = v4[lane + 64 * k];
    const float bias = barr[w * H + t];  // uniform -> scalar load

    __syncthreads();  // single drain: s_waitcnt vmcnt(0) + barrier

    float acc = 0.0f;
    const float4* lb4 = &wbuf[w][0];
#pragma unroll
    for (int k = 0; k < 8; ++k) {
        float4 a = lb4[k * 64 + lane];
        acc += a.x * bv[k].x + a.y * bv[k].y + a.z * bv[k].z + a.w * bv[k].w;
    }
    acc = wave_reduce_sum(acc);
    if (lane == 0) part[m * 4 * H + w * H + t] = acc + bias;
}

// Layer 0 partial: only Whh matters (Wih0 is [4H,1], folded into combine).
// Both biases folded here. grid 2048, block 256 = 4 waves = 4 gates.
__global__ __launch_bounds__(256)
void lstm0_partial(const float* __restrict__ Whh,
                   const float* __restrict__ bih, const float* __restrict__ bhh,
                   const float* __restrict__ hin,  // [H]
                   float* __restrict__ part)       // [4H]
{
    __shared__ float4 wbuf[4][512];
    const int t = blockIdx.x;
    const int w = threadIdx.x >> 6;
    const int lane = threadIdx.x & 63;

    const float* row = Whh + (size_t)(w * H + t) * H;
    float* lbase = (float*)&wbuf[w][0];
#pragma unroll
    for (int k = 0; k < 8; ++k)
        gl_lds16(row + k * 256 + lane * 4, lbase + k * 256);

    float4 bv[8];
    const float4* v4 = (const float4*)hin;
#pragma unroll
    for (int k = 0; k < 8; ++k) bv[k] = v4[lane + 64 * k];
    const float bias = bih[w * H + t] + bhh[w * H + t];

    __syncthreads();

    float acc = 0.0f;
    const float4* lb4 = &wbuf[w][0];
#pragma unroll
    for (int k = 0; k < 8; ++k) {
        float4 a = lb4[k * 64 + lane];
        acc += a.x * bv[k].x + a.y * bv[k].y + a.z * bv[k].z + a.w * bv[k].w;
    }
    acc = wave_reduce_sum(acc);
    if (lane == 0) part[w * H + t] = acc + bias;
}

// Combine for layers 1,2: gates = part_ih + part_hh (biases already folded).
__global__ __launch_bounds__(256)
void lstm_combine(const float* __restrict__ part,  // [2][4H]
                  const float* __restrict__ cin,
                  float* __restrict__ hout, float* __restrict__ cout)
{
    const int t = blockIdx.x * 256 + threadIdx.x;  // grid 8 -> 2048
    float gi = part[t]         + part[4 * H + t];
    float gf = part[H + t]     + part[5 * H + t];
    float gg = part[2 * H + t] + part[6 * H + t];
    float go = part[3 * H + t] + part[7 * H + t];
    float c2 = sigmoidf_(gf) * cin[t] + sigmoidf_(gi) * tanhf(gg);
    float h2 = sigmoidf_(go) * tanhf(c2);
    cout[t] = c2;
    hout[t] = h2;
}

// Combine for layer 0: add x * Wih0[gate] term.
__global__ __launch_bounds__(256)
void lstm0_combine(const float* __restrict__ part,  // [4H]
                   const float* __restrict__ Wih0,  // [4H]
                   const float* __restrict__ xs,    // [1]
                   const float* __restrict__ cin,
                   float* __restrict__ hout, float* __restrict__ cout)
{
    const int t = blockIdx.x * 256 + threadIdx.x;
    const float x = xs[0];
    float gi = part[t]         + x * Wih0[t];
    float gf = part[H + t]     + x * Wih0[H + t];
    float gg = part[2 * H + t] + x * Wih0[2 * H + t];
    float go = part[3 * H + t] + x * Wih0[3 * H + t];
    float c2 = sigmoidf_(gf) * cin[t] + sigmoidf_(gi) * tanhf(gg);
    float h2 = sigmoidf_(go) * tanhf(c2);
    cout[t] = c2;
    hout[t] = h2;
}

// y = dot(Wout, h) + bout   (single block)
__global__ __launch_bounds__(256)
void out_proj(const float* __restrict__ Wout,
              const float* __restrict__ bout,
              const float* __restrict__ h,
              float* __restrict__ y)
{
    __shared__ float partl[4];
    const int tid = threadIdx.x;
    const float4* W4 = (const float4*)Wout;
    const float4* h4 = (const float4*)h;
    float acc = 0.0f;
#pragma unroll
    for (int k = 0; k < 2; ++k) {
        int i = tid + 256 * k;
        float4 a = W4[i];
        float4 b = h4[i];
        acc += a.x * b.x + a.y * b.y + a.z * b.z + a.w * b.w;
    }
    acc = wave_reduce_sum(acc);
    if ((tid & 63) == 0) partl[tid >> 6] = acc;
    __syncthreads();
    if (tid == 0) y[0] = partl[0] + partl[1] + partl[2] + partl[3] + bout[0];
}

extern "C" void kernel_launch(void* const* d_in, const int* in_sizes, int n_in,
                              void* d_out, int out_size, void* d_ws, size_t ws_size,
                              hipStream_t stream) {
    const float* x    = (const float*)d_in[0];
    const float* hin  = (const float*)d_in[1];   // [3,1,H]
    const float* cin  = (const float*)d_in[2];   // [3,1,H]
    const float* Wih0 = (const float*)d_in[3];
    const float* Whh0 = (const float*)d_in[4];
    const float* bih0 = (const float*)d_in[5];
    const float* bhh0 = (const float*)d_in[6];
    const float* Wih1 = (const float*)d_in[7];
    const float* Whh1 = (const float*)d_in[8];
    const float* bih1 = (const float*)d_in[9];
    const float* bhh1 = (const float*)d_in[10];
    const float* Wih2 = (const float*)d_in[11];
    const float* Whh2 = (const float*)d_in[12];
    const float* bih2 = (const float*)d_in[13];
    const float* bhh2 = (const float*)d_in[14];
    const float* Wout = (const float*)d_in[15];
    const float* bout = (const float*)d_in[16];

    float* out = (float*)d_out;
    float* y  = out;              // [1]
    float* hN = out + 1;          // [3,H]
    float* cN = out + 1 + 3 * H;  // [3,H]

    float* part = (float*)d_ws;   // needs 2*4H floats = 64 KB scratch

    lstm0_partial<<<2048, 256, 0, stream>>>(Whh0, bih0, bhh0, hin, part);
    lstm0_combine<<<8, 256, 0, stream>>>(part, Wih0, x, cin, hN, cN);

    lstm_partial<<<4096, 256, 0, stream>>>(Wih1, Whh1, bih1, bhh1,
                                           hN, hin + H, part);
    lstm_combine<<<8, 256, 0, stream>>>(part, cin + H, hN + H, cN + H);

    lstm_partial<<<4096, 256, 0, stream>>>(Wih2, Whh2, bih2, bhh2,
                                           hN + H, hin + 2 * H, part);
    lstm_combine<<<8, 256, 0, stream>>>(part, cin + 2 * H, hN + 2 * H, cN + 2 * H);

    out_proj<<<1, 256, 0, stream>>>(Wout, bout, hN + 2 * H, y);
}

// Round 4
// 319.292 us; speedup vs baseline: 1.0520x; 1.0520x over previous
//
#include <hip/hip_runtime.h>
#include <math.h>

#define H 2048

__device__ __forceinline__ float sigmoidf_(float v) {
    return 1.0f / (1.0f + expf(-v));
}

__device__ __forceinline__ float wave_reduce_sum(float v) {
    v += __shfl_down(v, 32, 64);
    v += __shfl_down(v, 16, 64);
    v += __shfl_down(v, 8, 64);
    v += __shfl_down(v, 4, 64);
    v += __shfl_down(v, 2, 64);
    v += __shfl_down(v, 1, 64);
    return v;
}

// Layers 1,2 — persistent-wave, fully fused.
// 512 blocks x 256 thr = 2048 waves; wave gw owns output element t = gw.
// It holds x-vec and h-vec in registers (64 VGPRs, loaded once), streams the
// 8 weight rows {Wih,Whh} x {i,f,g,o} for element t (64 KB) with no barriers
// and no LDS, wave-reduces each dot, and computes c2/h2 in-wave.
__global__ __launch_bounds__(256, 2)
void lstm_layer(const float* __restrict__ Wih, const float* __restrict__ Whh,
                const float* __restrict__ bih, const float* __restrict__ bhh,
                const float* __restrict__ xin,  // [H] prev-layer h
                const float* __restrict__ hin,  // [H]
                const float* __restrict__ cin,  // [H]
                float* __restrict__ hout, float* __restrict__ cout)
{
    const int t = blockIdx.x * 4 + (threadIdx.x >> 6);  // 0..2047
    const int lane = threadIdx.x & 63;

    // input vectors resident in registers for the whole kernel
    float4 xv[8], hv[8];
    const float4* x4 = (const float4*)xin;
    const float4* h4 = (const float4*)hin;
#pragma unroll
    for (int k = 0; k < 8; ++k) {
        xv[k] = x4[lane + 64 * k];
        hv[k] = h4[lane + 64 * k];
    }

    float gsum[4];
#pragma unroll 1   // keep gate iterations sequential: bounded VGPR, continuous load stream
    for (int g = 0; g < 4; ++g) {
        const float4* wi = (const float4*)(Wih + (size_t)(g * H + t) * H);
        const float4* wh = (const float4*)(Whh + (size_t)(g * H + t) * H);
        float ai = 0.0f, ah = 0.0f;   // two independent chains
#pragma unroll
        for (int k = 0; k < 8; ++k) {
            float4 a = wi[lane + 64 * k];
            float4 b = wh[lane + 64 * k];
            ai += a.x * xv[k].x + a.y * xv[k].y + a.z * xv[k].z + a.w * xv[k].w;
            ah += b.x * hv[k].x + b.y * hv[k].y + b.z * hv[k].z + b.w * hv[k].w;
        }
        gsum[g] = wave_reduce_sum(ai + ah);
    }

    if (lane == 0) {
        float gi = gsum[0] + bih[t]         + bhh[t];
        float gf = gsum[1] + bih[H + t]     + bhh[H + t];
        float gg = gsum[2] + bih[2 * H + t] + bhh[2 * H + t];
        float go = gsum[3] + bih[3 * H + t] + bhh[3 * H + t];
        float c2 = sigmoidf_(gf) * cin[t] + sigmoidf_(gi) * tanhf(gg);
        float h2 = sigmoidf_(go) * tanhf(c2);
        cout[t] = c2;
        hout[t] = h2;
    }
}

// Layer 0 — same persistent-wave shape; Wih0 is [4H,1] so its contribution is
// the scalar x * Wih0[g*H+t], folded into the tail.
__global__ __launch_bounds__(256, 2)
void lstm_layer0(const float* __restrict__ Wih0,  // [4H]
                 const float* __restrict__ Whh,   // [4H,H]
                 const float* __restrict__ bih, const float* __restrict__ bhh,
                 const float* __restrict__ xs,    // [1]
                 const float* __restrict__ hin, const float* __restrict__ cin,
                 float* __restrict__ hout, float* __restrict__ cout)
{
    const int t = blockIdx.x * 4 + (threadIdx.x >> 6);
    const int lane = threadIdx.x & 63;

    float4 hv[8];
    const float4* h4 = (const float4*)hin;
#pragma unroll
    for (int k = 0; k < 8; ++k) hv[k] = h4[lane + 64 * k];

    float gsum[4];
#pragma unroll 1
    for (int g = 0; g < 4; ++g) {
        const float4* wh = (const float4*)(Whh + (size_t)(g * H + t) * H);
        float a0 = 0.0f, a1 = 0.0f;
#pragma unroll
        for (int k = 0; k < 8; k += 2) {
            float4 a = wh[lane + 64 * k];
            float4 b = wh[lane + 64 * (k + 1)];
            a0 += a.x * hv[k].x + a.y * hv[k].y + a.z * hv[k].z + a.w * hv[k].w;
            a1 += b.x * hv[k+1].x + b.y * hv[k+1].y + b.z * hv[k+1].z + b.w * hv[k+1].w;
        }
        gsum[g] = wave_reduce_sum(a0 + a1);
    }

    if (lane == 0) {
        const float x = xs[0];
        float gi = gsum[0] + x * Wih0[t]         + bih[t]         + bhh[t];
        float gf = gsum[1] + x * Wih0[H + t]     + bih[H + t]     + bhh[H + t];
        float gg = gsum[2] + x * Wih0[2 * H + t] + bih[2 * H + t] + bhh[2 * H + t];
        float go = gsum[3] + x * Wih0[3 * H + t] + bih[3 * H + t] + bhh[3 * H + t];
        float c2 = sigmoidf_(gf) * cin[t] + sigmoidf_(gi) * tanhf(gg);
        float h2 = sigmoidf_(go) * tanhf(c2);
        cout[t] = c2;
        hout[t] = h2;
    }
}

// y = dot(Wout, h) + bout   (single block)
__global__ __launch_bounds__(256)
void out_proj(const float* __restrict__ Wout,
              const float* __restrict__ bout,
              const float* __restrict__ h,
              float* __restrict__ y)
{
    __shared__ float partl[4];
    const int tid = threadIdx.x;
    const float4* W4 = (const float4*)Wout;
    const float4* h4 = (const float4*)h;
    float acc = 0.0f;
#pragma unroll
    for (int k = 0; k < 2; ++k) {
        int i = tid + 256 * k;
        float4 a = W4[i];
        float4 b = h4[i];
        acc += a.x * b.x + a.y * b.y + a.z * b.z + a.w * b.w;
    }
    acc = wave_reduce_sum(acc);
    if ((tid & 63) == 0) partl[tid >> 6] = acc;
    __syncthreads();
    if (tid == 0) y[0] = partl[0] + partl[1] + partl[2] + partl[3] + bout[0];
}

extern "C" void kernel_launch(void* const* d_in, const int* in_sizes, int n_in,
                              void* d_out, int out_size, void* d_ws, size_t ws_size,
                              hipStream_t stream) {
    const float* x    = (const float*)d_in[0];
    const float* hin  = (const float*)d_in[1];   // [3,1,H]
    const float* cin  = (const float*)d_in[2];   // [3,1,H]
    const float* Wih0 = (const float*)d_in[3];
    const float* Whh0 = (const float*)d_in[4];
    const float* bih0 = (const float*)d_in[5];
    const float* bhh0 = (const float*)d_in[6];
    const float* Wih1 = (const float*)d_in[7];
    const float* Whh1 = (const float*)d_in[8];
    const float* bih1 = (const float*)d_in[9];
    const float* bhh1 = (const float*)d_in[10];
    const float* Wih2 = (const float*)d_in[11];
    const float* Whh2 = (const float*)d_in[12];
    const float* bih2 = (const float*)d_in[13];
    const float* bhh2 = (const float*)d_in[14];
    const float* Wout = (const float*)d_in[15];
    const float* bout = (const float*)d_in[16];

    float* out = (float*)d_out;
    float* y  = out;              // [1]
    float* hN = out + 1;          // [3,H]
    float* cN = out + 1 + 3 * H;  // [3,H]

    lstm_layer0<<<512, 256, 0, stream>>>(Wih0, Whh0, bih0, bhh0, x,
                                         hin, cin, hN, cN);
    lstm_layer<<<512, 256, 0, stream>>>(Wih1, Whh1, bih1, bhh1,
                                        hN, hin + H, cin + H,
                                        hN + H, cN + H);
    lstm_layer<<<512, 256, 0, stream>>>(Wih2, Whh2, bih2, bhh2,
                                        hN + H, hin + 2 * H, cin + 2 * H,
                                        hN + 2 * H, cN + 2 * H);
    out_proj<<<1, 256, 0, stream>>>(Wout, bout, hN + 2 * H, y);
}